// Round 5
// baseline (287.739 us; speedup 1.0000x reference)
//
#include <hip/hip_runtime.h>
#include <stdint.h>

// Problem constants (from reference: B=16,T=2048,D=256,K=8192)
#define NROWS 32768
#define DDIM  256
#define KCB   8192
#define KQUART 2048        // each block handles a quarter of the codebook
#define NT    (KQUART / 32) // 64 E-tiles of 32 entries

typedef __attribute__((ext_vector_type(8)))  short short8;  // 8 bf16 (4 VGPRs)
typedef __attribute__((ext_vector_type(16))) float f32x16;  // 32x32 acc (16 VGPRs)

__device__ __forceinline__ unsigned short f2bf(float f) {
  unsigned u = __builtin_bit_cast(unsigned, f);
  return (unsigned short)((u + 0x7FFFu + ((u >> 16) & 1u)) >> 16); // RNE
}

__device__ __forceinline__ void gload_lds16(const void* g, void* l) {
  __builtin_amdgcn_global_load_lds(
      (const __attribute__((address_space(1))) unsigned int*)g,
      (__attribute__((address_space(3))) unsigned int*)l, 16, 0, 0);
}

// ---------------- prep: embed fp32 -> bf16, norm-pair (hi,lo bf16) blocks ----------------
// nrm16[e] = 16 bytes: [bf16(-0.5|e|^2), bf16(residual), 12 zero bytes] — consumed
// directly as the 17th K-chunk MFMA A-fragment.
__global__ void prep_embed(const float* __restrict__ embed,
                           unsigned short* __restrict__ ebf,
                           unsigned int* __restrict__ nrm16) {
  const int t = threadIdx.x;
  const int lane = t & 63, w = t >> 6;
  const int row = blockIdx.x * 4 + w;
  const float4 v = *(const float4*)(embed + (size_t)row * DDIM + lane * 4);
  ushort4 b;
  b.x = f2bf(v.x); b.y = f2bf(v.y); b.z = f2bf(v.z); b.w = f2bf(v.w);
  *(ushort4*)(ebf + (size_t)row * DDIM + lane * 4) = b;
  float sq = v.x * v.x + v.y * v.y + v.z * v.z + v.w * v.w;
  #pragma unroll
  for (int m = 32; m; m >>= 1) sq += __shfl_xor(sq, m);
  if (lane == 0) {
    const float nv = -0.5f * sq;
    const unsigned hi = f2bf(nv);
    const float hf = __builtin_bit_cast(float, hi << 16);
    const unsigned lo = f2bf(nv - hf);
    uint4 nb; nb.x = hi | (lo << 16); nb.y = 0; nb.z = 0; nb.w = 0;
    *(uint4*)(nrm16 + (size_t)row * 4) = nb;
  }
}

// ---------------- main: swapped-operand 32x32x16 GEMM + lane-local top-2 screen --------
// D = E_tile x X^T : D col (lane&31) = x-row, D row = codebook entry. Each lane
// screens 2 x-rows with 4 classes x top-2 (+exact index), full-precision compares.
// Counted-vmcnt 4-buffer pipeline: stage(i+1) after barrier; s_waitcnt vmcnt(4)
// keeps the prefetch in flight across the barrier (no vmcnt(0) drain).
// grid = 512: bid>>2 = M-tile (256 rows), bid&3 = K-quarter (2048 codes)
__launch_bounds__(256, 2)
__global__ void vq_main(const float* __restrict__ x,
                        const unsigned short* __restrict__ ebf,
                        const unsigned int* __restrict__ nrm16,
                        unsigned int* __restrict__ cand) {
  __shared__ __align__(16) unsigned char sm[4 * 16384]; // 4 x 16KB E-tile buffers
  const int t = threadIdx.x;
  const int lane = t & 63, w = t >> 6;
  const int l31 = lane & 31, hi2 = lane >> 5;
  const int mtile = blockIdx.x >> 2, q = blockIdx.x & 3;
  const int rowbase = mtile * 256 + w * 64;
  const int qbase = q * KQUART;

  // staging source: pre-swizzled global (involution: phys slot p holds logical p^(r&7))
  const char* gs = (const char*)ebf + (size_t)qbase * 512 + (size_t)(t >> 5) * 512 +
                   (((t & 31) ^ ((t >> 5) & 7)) << 4);
  // norm-fragment walking pointer (per-lane row l31)
  const char* np = (const char*)nrm16 + ((size_t)(qbase + l31) << 4);

  #define STAGE(BUF)                                                    \
    {                                                                   \
      _Pragma("unroll")                                                 \
      for (int i = 0; i < 4; ++i)                                       \
        gload_lds16(gs + i * 4096, &sm[(BUF) * 16384 + i * 4096 + w * 1024]); \
      gs += 16384;                                                      \
    }

  STAGE(0) // tile 0 into buf 0

  // --- B fragments: X rows resident. B[k][n]: n = lane&31 (x-row), k = kc*16 + 8*hi2 + e
  short8 bfr[2][16];
  #pragma unroll
  for (int xb = 0; xb < 2; ++xb) {
    const float* xr = x + (size_t)(rowbase + xb * 32 + l31) * DDIM + hi2 * 8;
    #pragma unroll
    for (int kc = 0; kc < 16; ++kc) {
      const float4 f0 = *(const float4*)(xr + kc * 16);
      const float4 f1 = *(const float4*)(xr + kc * 16 + 4);
      short8 bb;
      bb[0] = (short)f2bf(f0.x); bb[1] = (short)f2bf(f0.y);
      bb[2] = (short)f2bf(f0.z); bb[3] = (short)f2bf(f0.w);
      bb[4] = (short)f2bf(f1.x); bb[5] = (short)f2bf(f1.y);
      bb[6] = (short)f2bf(f1.z); bb[7] = (short)f2bf(f1.w);
      bfr[xb][kc] = bb;
    }
  }

  // B fragment for the norm chunk: X_ext[:,256]=X_ext[:,257]=1 -> lanes<32: {1,1,0..}
  short8 bn = {0, 0, 0, 0, 0, 0, 0, 0};
  if (hi2 == 0) { bn[0] = (short)0x3F80; bn[1] = (short)0x3F80; }

  // --- iter-invariant swizzled LDS read bases ---
  // read addr = baseoff[kc&3] + imm(BUF*16384 + (kc&12)<<5); phys slot = (2kc|hi2)^(l31&7)
  const int ab = l31 * 512 + ((hi2 ^ (lane & 1)) << 4);
  int baseoff[4];
  #pragma unroll
  for (int j = 0; j < 4; ++j)
    baseoff[j] = ab + ((j ^ ((lane >> 1) & 3)) << 5);

  // --- screen state: top-2 + exact idx per (x-block, class) ; class = acc-reg quad ---
  const float NEGINF = __builtin_bit_cast(float, 0xFF800000u);
  float v1[2][4], v2[2][4];
  int   i1[2][4], i2[2][4];
  #pragma unroll
  for (int xb = 0; xb < 2; ++xb)
    #pragma unroll
    for (int c = 0; c < 4; ++c) { v1[xb][c] = NEGINF; v2[xb][c] = NEGINF; i1[xb][c] = 0; i2[xb][c] = 0; }

  #define BODY(BUF, IT, DO_STAGE, VMASM)                                         \
    {                                                                            \
      if (DO_STAGE) STAGE(((BUF) + 1) & 3)                                       \
      asm volatile(VMASM ::: "memory");                                          \
      __builtin_amdgcn_s_barrier();                                              \
      const short8 an = __builtin_bit_cast(short8, *(const uint4*)np);           \
      np += 512;                                                                 \
      f32x16 acc0 = {0.f, 0.f, 0.f, 0.f, 0.f, 0.f, 0.f, 0.f,                     \
                     0.f, 0.f, 0.f, 0.f, 0.f, 0.f, 0.f, 0.f};                    \
      f32x16 acc1 = acc0;                                                        \
      _Pragma("unroll")                                                          \
      for (int kc = 0; kc < 16; ++kc) {                                          \
        const short8 ae = *(const short8*)(&sm[(BUF) * 16384 + ((kc & 12) << 5)] \
                                           + baseoff[kc & 3]);                   \
        acc0 = __builtin_amdgcn_mfma_f32_32x32x16_bf16(ae, bfr[0][kc], acc0, 0, 0, 0); \
        acc1 = __builtin_amdgcn_mfma_f32_32x32x16_bf16(ae, bfr[1][kc], acc1, 0, 0, 0); \
      }                                                                          \
      acc0 = __builtin_amdgcn_mfma_f32_32x32x16_bf16(an, bn, acc0, 0, 0, 0);     \
      acc1 = __builtin_amdgcn_mfma_f32_32x32x16_bf16(an, bn, acc1, 0, 0, 0);     \
      const int idxb = (IT) * 32 + 4 * hi2;                                      \
      _Pragma("unroll")                                                          \
      for (int r = 0; r < 16; ++r) {                                             \
        const int idxr = idxb + (r & 3) + 8 * (r >> 2);                          \
        const int c = r >> 2;                                                    \
        _Pragma("unroll")                                                        \
        for (int xb = 0; xb < 2; ++xb) {                                         \
          const float s = xb ? acc1[r] : acc0[r];                                \
          const bool a = s > v1[xb][c];                                          \
          const bool b = s > v2[xb][c];                                          \
          const float nv2 = __builtin_amdgcn_fmed3f(s, v1[xb][c], v2[xb][c]);    \
          i2[xb][c] = a ? i1[xb][c] : (b ? idxr : i2[xb][c]);                    \
          v2[xb][c] = nv2;                                                       \
          v1[xb][c] = fmaxf(v1[xb][c], s);                                       \
          i1[xb][c] = a ? idxr : i1[xb][c];                                      \
        }                                                                        \
      }                                                                          \
    }

  #pragma unroll 1
  for (int it4 = 0; it4 < NT - 4; it4 += 4) {
    BODY(0, it4 + 0, 1, "s_waitcnt vmcnt(4)")
    BODY(1, it4 + 1, 1, "s_waitcnt vmcnt(4)")
    BODY(2, it4 + 2, 1, "s_waitcnt vmcnt(4)")
    BODY(3, it4 + 3, 1, "s_waitcnt vmcnt(4)")
  }
  BODY(0, NT - 4, 1, "s_waitcnt vmcnt(4)")
  BODY(1, NT - 3, 1, "s_waitcnt vmcnt(4)")
  BODY(2, NT - 2, 1, "s_waitcnt vmcnt(4)")   // stages tile NT-1
  BODY(3, NT - 1, 0, "s_waitcnt vmcnt(0)")   // last tile: full drain
  #undef BODY
  #undef STAGE

  // --- merge: per x-row, 8 local (v,i) pairs + 8 from partner lane (^32) -> top-4 ---
  #define INS(bv, bi)                                                              \
  { const bool g0 = (bv) > t0, g1 = (bv) > t1, g2 = (bv) > t2, g3 = (bv) > t3;     \
    const float n1 = g0 ? t0 : (g1 ? (bv) : t1); const int m1 = g0 ? j0 : (g1 ? (bi) : j1); \
    const float n2 = g1 ? t1 : (g2 ? (bv) : t2); const int m2 = g1 ? j1 : (g2 ? (bi) : j2); \
    const float n3 = g2 ? t2 : (g3 ? (bv) : t3); const int m3 = g2 ? j2 : (g3 ? (bi) : j3); \
    t0 = g0 ? (bv) : t0; j0 = g0 ? (bi) : j0;                                      \
    t1 = n1; j1 = m1; t2 = n2; j2 = m2; t3 = n3; j3 = m3; }
  #pragma unroll
  for (int xb = 0; xb < 2; ++xb) {
    float t0 = NEGINF, t1 = NEGINF, t2 = NEGINF, t3 = NEGINF;
    int   j0 = 0, j1 = 0, j2 = 0, j3 = 0;
    #pragma unroll
    for (int c = 0; c < 4; ++c) {
      INS(v1[xb][c], i1[xb][c])
      INS(v2[xb][c], i2[xb][c])
    }
    // exchange with the partner lane holding the same x-row (lane ^ 32)
    const float p0 = __shfl_xor(t0, 32), p1 = __shfl_xor(t1, 32);
    const float p2 = __shfl_xor(t2, 32), p3 = __shfl_xor(t3, 32);
    const int   q0 = __shfl_xor(j0, 32), q1 = __shfl_xor(j1, 32);
    const int   q2 = __shfl_xor(j2, 32), q3 = __shfl_xor(j3, 32);
    INS(p0, q0) INS(p1, q1) INS(p2, q2) INS(p3, q3)
    if (hi2 == 0) {
      const int row = rowbase + xb * 32 + l31;
      // stuff 11-bit local index into low mantissa bits (encoding only; all
      // selection above used full-precision values)
      uint4 c4;
      c4.x = (__builtin_bit_cast(unsigned int, t0) & 0xFFFFF800u) | (unsigned int)j0;
      c4.y = (__builtin_bit_cast(unsigned int, t1) & 0xFFFFF800u) | (unsigned int)j1;
      c4.z = (__builtin_bit_cast(unsigned int, t2) & 0xFFFFF800u) | (unsigned int)j2;
      c4.w = (__builtin_bit_cast(unsigned int, t3) & 0xFFFFF800u) | (unsigned int)j3;
      *(uint4*)(cand + (size_t)row * 16 + q * 4) = c4;
    }
  }
  #undef INS
}

// ---------------- rescore: prefiltered exact distances over 16 candidates ----------------
__global__ void rescore_gather(const float* __restrict__ x,
                               const float* __restrict__ embed,
                               const unsigned int* __restrict__ cand,
                               float* __restrict__ out) {
  const int t = threadIdx.x;
  const int lane = t & 63, w = t >> 6;
  const int row = blockIdx.x * 4 + w;

  uint4 cv[4];
  #pragma unroll
  for (int qq = 0; qq < 4; ++qq)
    cv[qq] = *(const uint4*)(cand + (size_t)row * 16 + qq * 4);
  unsigned int cw[16];
  #pragma unroll
  for (int qq = 0; qq < 4; ++qq) {
    cw[qq * 4 + 0] = cv[qq].x; cw[qq * 4 + 1] = cv[qq].y;
    cw[qq * 4 + 2] = cv[qq].z; cw[qq * 4 + 3] = cv[qq].w;
  }
  float mx = -__builtin_inff();
  #pragma unroll
  for (int c = 0; c < 16; ++c) mx = fmaxf(mx, __builtin_bit_cast(float, cw[c]));
  // true-best bf16 screen value trails mx by <= 2x bf16 noise (~0.4) + stuff
  // quantization (~0.06) + norm-fold error (~1e-3); 1.0 is ample margin
  const float thr = mx - 1.0f;

  const float4 xv = *(const float4*)(x + (size_t)row * DDIM + lane * 4);
  double bd = 1e300;
  int bi = 0x7fffffff;
  float4 bv = {0.f, 0.f, 0.f, 0.f};
  #pragma unroll
  for (int c = 0; c < 16; ++c) {
    const float f = __builtin_bit_cast(float, cw[c]);
    if (f >= thr) { // wave-uniform branch
      const int idx = (int)(cw[c] & 0x7FFu) + (c >> 2) * KQUART;
      const float4 ev = *(const float4*)(embed + (size_t)idx * DDIM + lane * 4);
      const float d0 = xv.x - ev.x, d1 = xv.y - ev.y;
      const float d2 = xv.z - ev.z, d3 = xv.w - ev.w;
      double d = (double)d0 * d0 + (double)d1 * d1 + (double)d2 * d2 + (double)d3 * d3;
      #pragma unroll
      for (int m = 32; m; m >>= 1) d += __shfl_xor(d, m);
      const bool better = (d < bd) || (d == bd && idx < bi); // tie -> lowest index
      bd = better ? d : bd;
      bi = better ? idx : bi;
      bv.x = better ? ev.x : bv.x; bv.y = better ? ev.y : bv.y;
      bv.z = better ? ev.z : bv.z; bv.w = better ? ev.w : bv.w;
    }
  }
  *(float4*)(out + (size_t)row * DDIM + lane * 4) = bv;
}

extern "C" void kernel_launch(void* const* d_in, const int* in_sizes, int n_in,
                              void* d_out, int out_size, void* d_ws, size_t ws_size,
                              hipStream_t stream) {
  const float* x     = (const float*)d_in[0];
  const float* embed = (const float*)d_in[1];
  float* out = (float*)d_out;

  char* wsb = (char*)d_ws;
  unsigned short* ebf = (unsigned short*)wsb;                               // 4 MB bf16 codebook
  unsigned int* nrm16 = (unsigned int*)(wsb + (size_t)KCB * DDIM * 2);      // 128 KB norm blocks
  unsigned int* cand =
      (unsigned int*)(wsb + (size_t)KCB * DDIM * 2 + (size_t)KCB * 16);     // 2 MB candidates

  hipLaunchKernelGGL(prep_embed, dim3(KCB / 4), dim3(256), 0, stream, embed, ebf, nrm16);
  hipLaunchKernelGGL(vq_main, dim3(512), dim3(256), 0, stream, x, ebf, nrm16, cand);
  hipLaunchKernelGGL(rescore_gather, dim3(NROWS / 4), dim3(256), 0, stream, x, embed, cand, out);
}

// Round 6
// 283.730 us; speedup vs baseline: 1.0141x; 1.0141x over previous
//
#include <hip/hip_runtime.h>
#include <stdint.h>

// Problem constants (from reference: B=16,T=2048,D=256,K=8192)
#define NROWS 32768
#define DDIM  256
#define KCB   8192
#define KQUART 2048        // each block handles a quarter of the codebook
#define NT    (KQUART / 32) // 64 E-tiles of 32 entries

typedef __attribute__((ext_vector_type(8)))  short short8;  // 8 bf16 (4 VGPRs)
typedef __attribute__((ext_vector_type(16))) float f32x16;  // 32x32 acc (16 VGPRs)

__device__ __forceinline__ unsigned short f2bf(float f) {
  unsigned u = __builtin_bit_cast(unsigned, f);
  return (unsigned short)((u + 0x7FFFu + ((u >> 16) & 1u)) >> 16); // RNE
}

__device__ __forceinline__ void gload_lds16(const void* g, void* l) {
  __builtin_amdgcn_global_load_lds(
      (const __attribute__((address_space(1))) unsigned int*)g,
      (__attribute__((address_space(3))) unsigned int*)l, 16, 0, 0);
}

// ---------------- prep: embed fp32 -> bf16, norm-pair (hi,lo bf16) blocks ----------------
__global__ void prep_embed(const float* __restrict__ embed,
                           unsigned short* __restrict__ ebf,
                           unsigned int* __restrict__ nrm16) {
  const int t = threadIdx.x;
  const int lane = t & 63, w = t >> 6;
  const int row = blockIdx.x * 4 + w;
  const float4 v = *(const float4*)(embed + (size_t)row * DDIM + lane * 4);
  ushort4 b;
  b.x = f2bf(v.x); b.y = f2bf(v.y); b.z = f2bf(v.z); b.w = f2bf(v.w);
  *(ushort4*)(ebf + (size_t)row * DDIM + lane * 4) = b;
  float sq = v.x * v.x + v.y * v.y + v.z * v.z + v.w * v.w;
  #pragma unroll
  for (int m = 32; m; m >>= 1) sq += __shfl_xor(sq, m);
  if (lane == 0) {
    const float nv = -0.5f * sq;
    const unsigned hi = f2bf(nv);
    const float hf = __builtin_bit_cast(float, hi << 16);
    const unsigned lo = f2bf(nv - hf);
    uint4 nb; nb.x = hi | (lo << 16); nb.y = 0; nb.z = 0; nb.w = 0;
    *(uint4*)(nrm16 + (size_t)row * 4) = nb;
  }
}

// ---------------- main: swapped-operand 32x32x16 GEMM + lane-local top-2 screen --------
// Identical semantics to the R5-verified kernel; changes are resource-shaping only:
// (1) waves_per_eu(2,2) -> 256-VGPR budget (kills the 27MB scratch spill),
// (2) named X-fragment registers (no spill-prone 1KB local array),
// (3) norm fragment double-buffered & issued BEFORE the stage -> counted vmcnt(5)
//     keeps the 4 stage-loads + 1 norm-load in flight across every barrier.
__attribute__((amdgpu_flat_work_group_size(256, 256)))
__attribute__((amdgpu_waves_per_eu(2, 2)))
__global__ void vq_main(const float* __restrict__ x,
                        const unsigned short* __restrict__ ebf,
                        const unsigned int* __restrict__ nrm16,
                        unsigned int* __restrict__ cand) {
  __shared__ __align__(16) unsigned char sm[4 * 16384]; // 4 x 16KB E-tile buffers
  const int t = threadIdx.x;
  const int lane = t & 63, w = t >> 6;
  const int l31 = lane & 31, hi2 = lane >> 5;
  const int mtile = blockIdx.x >> 2, q = blockIdx.x & 3;
  const int rowbase = mtile * 256 + w * 64;
  const int qbase = q * KQUART;

  // staging source: pre-swizzled global (involution: phys slot p holds logical p^(r&7))
  const char* gs = (const char*)ebf + (size_t)qbase * 512 + (size_t)(t >> 5) * 512 +
                   (((t & 31) ^ ((t >> 5) & 7)) << 4);
  // norm-fragment walking pointer (per-lane row l31)
  const char* np = (const char*)nrm16 + ((size_t)(qbase + l31) << 4);

  #define STAGE(BUF)                                                          \
    {                                                                         \
      _Pragma("unroll")                                                       \
      for (int i = 0; i < 4; ++i)                                             \
        gload_lds16(gs + i * 4096, &sm[(BUF) * 16384 + i * 4096 + w * 1024]); \
      gs += 16384;                                                            \
    }

  STAGE(0) // tile 0 into buf 0

  // --- B fragments: X rows resident in NAMED registers ---
  // B[k][n]: n = lane&31 (x-row), k = kc*16 + 8*hi2 + e
  short8 b0_0, b0_1, b0_2, b0_3, b0_4, b0_5, b0_6, b0_7,
         b0_8, b0_9, b0_10, b0_11, b0_12, b0_13, b0_14, b0_15;
  short8 b1_0, b1_1, b1_2, b1_3, b1_4, b1_5, b1_6, b1_7,
         b1_8, b1_9, b1_10, b1_11, b1_12, b1_13, b1_14, b1_15;
  const float* xr0 = x + (size_t)(rowbase + l31) * DDIM + hi2 * 8;
  const float* xr1 = xr0 + 32 * DDIM;

  #define XFRAG(VAR, XR, KC)                                              \
    {                                                                     \
      const float4 f0 = *(const float4*)((XR) + (KC) * 16);               \
      const float4 f1 = *(const float4*)((XR) + (KC) * 16 + 4);           \
      short8 bb;                                                          \
      bb[0] = (short)f2bf(f0.x); bb[1] = (short)f2bf(f0.y);               \
      bb[2] = (short)f2bf(f0.z); bb[3] = (short)f2bf(f0.w);               \
      bb[4] = (short)f2bf(f1.x); bb[5] = (short)f2bf(f1.y);               \
      bb[6] = (short)f2bf(f1.z); bb[7] = (short)f2bf(f1.w);               \
      VAR = bb;                                                           \
    }
  XFRAG(b0_0, xr0, 0)  XFRAG(b0_1, xr0, 1)  XFRAG(b0_2, xr0, 2)  XFRAG(b0_3, xr0, 3)
  XFRAG(b0_4, xr0, 4)  XFRAG(b0_5, xr0, 5)  XFRAG(b0_6, xr0, 6)  XFRAG(b0_7, xr0, 7)
  XFRAG(b0_8, xr0, 8)  XFRAG(b0_9, xr0, 9)  XFRAG(b0_10, xr0, 10) XFRAG(b0_11, xr0, 11)
  XFRAG(b0_12, xr0, 12) XFRAG(b0_13, xr0, 13) XFRAG(b0_14, xr0, 14) XFRAG(b0_15, xr0, 15)
  XFRAG(b1_0, xr1, 0)  XFRAG(b1_1, xr1, 1)  XFRAG(b1_2, xr1, 2)  XFRAG(b1_3, xr1, 3)
  XFRAG(b1_4, xr1, 4)  XFRAG(b1_5, xr1, 5)  XFRAG(b1_6, xr1, 6)  XFRAG(b1_7, xr1, 7)
  XFRAG(b1_8, xr1, 8)  XFRAG(b1_9, xr1, 9)  XFRAG(b1_10, xr1, 10) XFRAG(b1_11, xr1, 11)
  XFRAG(b1_12, xr1, 12) XFRAG(b1_13, xr1, 13) XFRAG(b1_14, xr1, 14) XFRAG(b1_15, xr1, 15)
  #undef XFRAG

  // B fragment for the norm chunk: lanes<32: {1,1,0..}
  short8 bn = {0, 0, 0, 0, 0, 0, 0, 0};
  if (hi2 == 0) { bn[0] = (short)0x3F80; bn[1] = (short)0x3F80; }

  // --- iter-invariant swizzled LDS read offsets (phys chunk = (2kc|hi2)^(l31&7)) ---
  const int ab = l31 * 512 + ((hi2 ^ (lane & 1)) << 4);
  const int s2 = (lane >> 1) & 3;
  const int bo0 = ab + ((0 ^ s2) << 5);
  const int bo1 = ab + ((1 ^ s2) << 5);
  const int bo2 = ab + ((2 ^ s2) << 5);
  const int bo3 = ab + ((3 ^ s2) << 5);

  // --- screen state: top-2 + exact idx per (x-block, class) ---
  const float NEGINF = __builtin_bit_cast(float, 0xFF800000u);
  float v1[2][4], v2[2][4];
  int   i1[2][4], i2[2][4];
  #pragma unroll
  for (int xb = 0; xb < 2; ++xb)
    #pragma unroll
    for (int c = 0; c < 4; ++c) { v1[xb][c] = NEGINF; v2[xb][c] = NEGINF; i1[xb][c] = 0; i2[xb][c] = 0; }

  // norm-fragment pipeline: anA holds tile IT, prefetch next into the partner reg
  short8 anA, anB;
  anA = __builtin_bit_cast(short8, *(const uint4*)np); np += 512;

  #define KSTEP(BUF, IMM, BO, V0, V1r)                                             \
    {                                                                              \
      const short8 ae = *(const short8*)(&sm[(BUF) * 16384] + (IMM) + (BO));       \
      acc0 = __builtin_amdgcn_mfma_f32_32x32x16_bf16(ae, V0, acc0, 0, 0, 0);       \
      acc1 = __builtin_amdgcn_mfma_f32_32x32x16_bf16(ae, V1r, acc1, 0, 0, 0);      \
    }

  #define BODY(BUF, IT, DO_STAGE, ANC, ANN, VMASM)                               \
    {                                                                            \
      if (DO_STAGE) {                                                            \
        ANN = __builtin_bit_cast(short8, *(const uint4*)np); np += 512;          \
        STAGE(((BUF) + 1) & 3)                                                   \
      }                                                                          \
      asm volatile(VMASM ::: "memory");                                          \
      __builtin_amdgcn_s_barrier();                                              \
      f32x16 acc0 = {0.f, 0.f, 0.f, 0.f, 0.f, 0.f, 0.f, 0.f,                     \
                     0.f, 0.f, 0.f, 0.f, 0.f, 0.f, 0.f, 0.f};                    \
      f32x16 acc1 = acc0;                                                        \
      KSTEP(BUF, 0, bo0, b0_0, b1_0)     KSTEP(BUF, 0, bo1, b0_1, b1_1)          \
      KSTEP(BUF, 0, bo2, b0_2, b1_2)     KSTEP(BUF, 0, bo3, b0_3, b1_3)          \
      KSTEP(BUF, 128, bo0, b0_4, b1_4)   KSTEP(BUF, 128, bo1, b0_5, b1_5)        \
      KSTEP(BUF, 128, bo2, b0_6, b1_6)   KSTEP(BUF, 128, bo3, b0_7, b1_7)        \
      KSTEP(BUF, 256, bo0, b0_8, b1_8)   KSTEP(BUF, 256, bo1, b0_9, b1_9)        \
      KSTEP(BUF, 256, bo2, b0_10, b1_10) KSTEP(BUF, 256, bo3, b0_11, b1_11)      \
      KSTEP(BUF, 384, bo0, b0_12, b1_12) KSTEP(BUF, 384, bo1, b0_13, b1_13)      \
      KSTEP(BUF, 384, bo2, b0_14, b1_14) KSTEP(BUF, 384, bo3, b0_15, b1_15)      \
      acc0 = __builtin_amdgcn_mfma_f32_32x32x16_bf16(ANC, bn, acc0, 0, 0, 0);    \
      acc1 = __builtin_amdgcn_mfma_f32_32x32x16_bf16(ANC, bn, acc1, 0, 0, 0);    \
      const int idxb = (IT) * 32 + 4 * hi2;                                      \
      _Pragma("unroll")                                                          \
      for (int r = 0; r < 16; ++r) {                                             \
        const int idxr = idxb + (r & 3) + 8 * (r >> 2);                          \
        const int c = r >> 2;                                                    \
        _Pragma("unroll")                                                        \
        for (int xb = 0; xb < 2; ++xb) {                                         \
          const float s = xb ? acc1[r] : acc0[r];                                \
          const bool a = s > v1[xb][c];                                          \
          const bool b = s > v2[xb][c];                                          \
          const float nv2 = __builtin_amdgcn_fmed3f(s, v1[xb][c], v2[xb][c]);    \
          i2[xb][c] = a ? i1[xb][c] : (b ? idxr : i2[xb][c]);                    \
          v2[xb][c] = nv2;                                                       \
          v1[xb][c] = fmaxf(v1[xb][c], s);                                       \
          i1[xb][c] = a ? idxr : i1[xb][c];                                      \
        }                                                                        \
      }                                                                          \
    }

  #pragma unroll 1
  for (int it4 = 0; it4 < NT - 4; it4 += 4) {
    BODY(0, it4 + 0, 1, anA, anB, "s_waitcnt vmcnt(5)")
    BODY(1, it4 + 1, 1, anB, anA, "s_waitcnt vmcnt(5)")
    BODY(2, it4 + 2, 1, anA, anB, "s_waitcnt vmcnt(5)")
    BODY(3, it4 + 3, 1, anB, anA, "s_waitcnt vmcnt(5)")
  }
  BODY(0, NT - 4, 1, anA, anB, "s_waitcnt vmcnt(5)")
  BODY(1, NT - 3, 1, anB, anA, "s_waitcnt vmcnt(5)")
  BODY(2, NT - 2, 1, anA, anB, "s_waitcnt vmcnt(5)")   // stages tile NT-1 (buf3)
  BODY(3, NT - 1, 0, anB, anA, "s_waitcnt vmcnt(0)")   // last tile: full drain
  #undef BODY
  #undef KSTEP
  #undef STAGE

  // --- merge: per x-row, 8 local (v,i) pairs + 8 from partner lane (^32) -> top-4 ---
  #define INS(bv, bi)                                                              \
  { const bool g0 = (bv) > t0, g1 = (bv) > t1, g2 = (bv) > t2, g3 = (bv) > t3;     \
    const float n1 = g0 ? t0 : (g1 ? (bv) : t1); const int m1 = g0 ? j0 : (g1 ? (bi) : j1); \
    const float n2 = g1 ? t1 : (g2 ? (bv) : t2); const int m2 = g1 ? j1 : (g2 ? (bi) : j2); \
    const float n3 = g2 ? t2 : (g3 ? (bv) : t3); const int m3 = g2 ? j2 : (g3 ? (bi) : j3); \
    t0 = g0 ? (bv) : t0; j0 = g0 ? (bi) : j0;                                      \
    t1 = n1; j1 = m1; t2 = n2; j2 = m2; t3 = n3; j3 = m3; }
  #pragma unroll
  for (int xb = 0; xb < 2; ++xb) {
    float t0 = NEGINF, t1 = NEGINF, t2 = NEGINF, t3 = NEGINF;
    int   j0 = 0, j1 = 0, j2 = 0, j3 = 0;
    #pragma unroll
    for (int c = 0; c < 4; ++c) {
      INS(v1[xb][c], i1[xb][c])
      INS(v2[xb][c], i2[xb][c])
    }
    const float p0 = __shfl_xor(t0, 32), p1 = __shfl_xor(t1, 32);
    const float p2 = __shfl_xor(t2, 32), p3 = __shfl_xor(t3, 32);
    const int   q0 = __shfl_xor(j0, 32), q1 = __shfl_xor(j1, 32);
    const int   q2 = __shfl_xor(j2, 32), q3 = __shfl_xor(j3, 32);
    INS(p0, q0) INS(p1, q1) INS(p2, q2) INS(p3, q3)
    if (hi2 == 0) {
      const int row = rowbase + xb * 32 + l31;
      // stuff 11-bit local index into low mantissa bits (encoding only; all
      // selection above used full-precision values)
      uint4 c4;
      c4.x = (__builtin_bit_cast(unsigned int, t0) & 0xFFFFF800u) | (unsigned int)j0;
      c4.y = (__builtin_bit_cast(unsigned int, t1) & 0xFFFFF800u) | (unsigned int)j1;
      c4.z = (__builtin_bit_cast(unsigned int, t2) & 0xFFFFF800u) | (unsigned int)j2;
      c4.w = (__builtin_bit_cast(unsigned int, t3) & 0xFFFFF800u) | (unsigned int)j3;
      *(uint4*)(cand + (size_t)row * 16 + q * 4) = c4;
    }
  }
  #undef INS
}

// ---------------- rescore: prefiltered exact distances over 16 candidates ----------------
__global__ void rescore_gather(const float* __restrict__ x,
                               const float* __restrict__ embed,
                               const unsigned int* __restrict__ cand,
                               float* __restrict__ out) {
  const int t = threadIdx.x;
  const int lane = t & 63, w = t >> 6;
  const int row = blockIdx.x * 4 + w;

  uint4 cv[4];
  #pragma unroll
  for (int qq = 0; qq < 4; ++qq)
    cv[qq] = *(const uint4*)(cand + (size_t)row * 16 + qq * 4);
  unsigned int cw[16];
  #pragma unroll
  for (int qq = 0; qq < 4; ++qq) {
    cw[qq * 4 + 0] = cv[qq].x; cw[qq * 4 + 1] = cv[qq].y;
    cw[qq * 4 + 2] = cv[qq].z; cw[qq * 4 + 3] = cv[qq].w;
  }
  float mx = -__builtin_inff();
  #pragma unroll
  for (int c = 0; c < 16; ++c) mx = fmaxf(mx, __builtin_bit_cast(float, cw[c]));
  const float thr = mx - 1.0f;

  const float4 xv = *(const float4*)(x + (size_t)row * DDIM + lane * 4);
  double bd = 1e300;
  int bi = 0x7fffffff;
  float4 bv = {0.f, 0.f, 0.f, 0.f};
  #pragma unroll
  for (int c = 0; c < 16; ++c) {
    const float f = __builtin_bit_cast(float, cw[c]);
    if (f >= thr) { // wave-uniform branch (NaN-stuffed padding compares false)
      const int idx = (int)(cw[c] & 0x7FFu) + (c >> 2) * KQUART;
      const float4 ev = *(const float4*)(embed + (size_t)idx * DDIM + lane * 4);
      const float d0 = xv.x - ev.x, d1 = xv.y - ev.y;
      const float d2 = xv.z - ev.z, d3 = xv.w - ev.w;
      double d = (double)d0 * d0 + (double)d1 * d1 + (double)d2 * d2 + (double)d3 * d3;
      #pragma unroll
      for (int m = 32; m; m >>= 1) d += __shfl_xor(d, m);
      const bool better = (d < bd) || (d == bd && idx < bi); // tie -> lowest index
      bd = better ? d : bd;
      bi = better ? idx : bi;
      bv.x = better ? ev.x : bv.x; bv.y = better ? ev.y : bv.y;
      bv.z = better ? ev.z : bv.z; bv.w = better ? ev.w : bv.w;
    }
  }
  *(float4*)(out + (size_t)row * DDIM + lane * 4) = bv;
}

extern "C" void kernel_launch(void* const* d_in, const int* in_sizes, int n_in,
                              void* d_out, int out_size, void* d_ws, size_t ws_size,
                              hipStream_t stream) {
  const float* x     = (const float*)d_in[0];
  const float* embed = (const float*)d_in[1];
  float* out = (float*)d_out;

  char* wsb = (char*)d_ws;
  unsigned short* ebf = (unsigned short*)wsb;                               // 4 MB bf16 codebook
  unsigned int* nrm16 = (unsigned int*)(wsb + (size_t)KCB * DDIM * 2);      // 128 KB norm blocks
  unsigned int* cand =
      (unsigned int*)(wsb + (size_t)KCB * DDIM * 2 + (size_t)KCB * 16);     // 2 MB candidates

  hipLaunchKernelGGL(prep_embed, dim3(KCB / 4), dim3(256), 0, stream, embed, ebf, nrm16);
  hipLaunchKernelGGL(vq_main, dim3(512), dim3(256), 0, stream, x, ebf, nrm16, cand);
  hipLaunchKernelGGL(rescore_gather, dim3(NROWS / 4), dim3(256), 0, stream, x, embed, cand, out);
}